// Round 3
// baseline (128.800 us; speedup 1.0000x reference)
//
#include <hip/hip_runtime.h>

#define NTH 256

#define PHI1 0.29504296f    // e^{-1.220703125}
#define PHI2 0.0075683594f  // e^{-4.8828125}
#define GCUT 18.0f          // Gaussian support cutoff: e^-18 = 1.5e-8

// Bank swizzle — conflict-free for all in-place strides; swz(i+128)=swz(i)+128
// so 128-aligned group regions preserve the pattern.
__device__ __forceinline__ int swz(int i) { return i ^ (((i >> 4) & 3) * 5); }

__device__ __forceinline__ float2 cmul(float2 a, float2 b) {
  return make_float2(a.x * b.x - a.y * b.y, a.x * b.y + a.y * b.x);
}

template <int W>
__device__ __forceinline__ float wsum(float v) {
#pragma unroll
  for (int off = 1; off < W; off <<= 1) v += __shfl_xor(v, off, 64);
  return v;
}

// P(idx): output frequency of storage slot idx after the DIF stage sequence.
template <int M>
__device__ __forceinline__ int prevM(int i) {
  if (M == 128)
    return ((i >> 5) & 3) | (((i >> 3) & 3) << 2) | (((i >> 1) & 3) << 4) | ((i & 1) << 6);
  else if (M == 256)
    return ((i & 3) << 6) | (((i >> 2) & 3) << 4) | (((i >> 4) & 3) << 2) | ((i >> 6) & 3);
  else if (M == 512)
    return ((i >> 7) & 3) | (((i >> 5) & 3) << 2) | (((i >> 3) & 3) << 4) |
           (((i >> 1) & 3) << 6) | ((i & 1) << 8);
  else if (M == 1024)
    return ((i >> 8) & 3) | (((i >> 6) & 3) << 2) | (((i >> 4) & 3) << 4) |
           (((i >> 2) & 3) << 6) | ((i & 3) << 8);
  else
    return ((i >> 9) & 3) | (((i >> 7) & 3) << 2) | (((i >> 5) & 3) << 4) |
           (((i >> 3) & 3) << 6) | (((i >> 1) & 3) << 8) | ((i & 1) << 10);
}

// In-place radix-4 DIF stage; twiddles in registers.
template <bool INV>
__device__ __forceinline__ void dif4(float2* A, int j, int ls, float astep) {
  const int s = 1 << ls;
  const int e = j & (s - 1);
  const int base = ((j >> ls) << (ls + 2)) | e;
  float2 w1;
  __sincosf(astep * (float)e, &w1.y, &w1.x);
  if (INV) w1.y = -w1.y;
  const float2 w2 = cmul(w1, w1);
  const float2 w3 = cmul(w2, w1);
  const float2 a0 = A[swz(base)];
  const float2 a1 = A[swz(base + s)];
  const float2 a2 = A[swz(base + 2 * s)];
  const float2 a3 = A[swz(base + 3 * s)];
  const float t0x = a0.x + a2.x, t0y = a0.y + a2.y;
  const float t1x = a0.x - a2.x, t1y = a0.y - a2.y;
  const float t2x = a1.x + a3.x, t2y = a1.y + a3.y;
  const float bdx = a1.x - a3.x, bdy = a1.y - a3.y;
  const float sgn = INV ? -1.0f : 1.0f;
  const float t3x = sgn * bdy, t3y = -sgn * bdx;
  A[swz(base)]         = make_float2(t0x + t2x, t0y + t2y);
  A[swz(base + s)]     = cmul(make_float2(t1x + t3x, t1y + t3y), w1);
  A[swz(base + 2 * s)] = cmul(make_float2(t0x - t2x, t0y - t2y), w2);
  A[swz(base + 3 * s)] = cmul(make_float2(t1x - t3x, t1y - t3y), w3);
}

// In-place radix-4 DIT stage (transpose network; forward only).
__device__ __forceinline__ void dit4(float2* A, int j, int ls, float astep) {
  const int s = 1 << ls;
  const int e = j & (s - 1);
  const int base = ((j >> ls) << (ls + 2)) | e;
  float2 w1;
  __sincosf(astep * (float)e, &w1.y, &w1.x);
  const float2 w2 = cmul(w1, w1);
  const float2 w3 = cmul(w2, w1);
  const float2 c0 = A[swz(base)];
  const float2 c1 = cmul(A[swz(base + s)], w1);
  const float2 c2 = cmul(A[swz(base + 2 * s)], w2);
  const float2 c3 = cmul(A[swz(base + 3 * s)], w3);
  const float t0x = c0.x + c2.x, t0y = c0.y + c2.y;
  const float t1x = c0.x - c2.x, t1y = c0.y - c2.y;
  const float t2x = c1.x + c3.x, t2y = c1.y + c3.y;
  const float bdx = c1.x - c3.x, bdy = c1.y - c3.y;
  const float t3x = bdy, t3y = -bdx;
  A[swz(base)]         = make_float2(t0x + t2x, t0y + t2y);
  A[swz(base + s)]     = make_float2(t1x + t3x, t1y + t3y);
  A[swz(base + 2 * s)] = make_float2(t0x - t2x, t0y - t2y);
  A[swz(base + 3 * s)] = make_float2(t1x - t3x, t1y - t3y);
}

__device__ __forceinline__ void r2pair(float2* A, int g) {
  const float2 a = A[swz(2 * g)];
  const float2 b = A[swz(2 * g + 1)];
  A[swz(2 * g)]     = make_float2(a.x + b.x, a.y + b.y);
  A[swz(2 * g + 1)] = make_float2(a.x - b.x, a.y - b.y);
}

template <int M> struct LMof { static constexpr int v =
  (M == 2048) ? 11 : (M == 1024) ? 10 : (M == 512) ? 9 : (M == 256) ? 8 : 7; };

// Block-wide in-place DIF: natural -> P-order. M in {1024, 2048}.
template <int M, bool INV>
__device__ __forceinline__ void dif_blk(float2* A) {
  constexpr int LM = LMof<M>::v;
  constexpr int NB = M / 4;
  const int tid = (int)threadIdx.x;
#pragma unroll
  for (int ls = LM - 2; ls >= (LM & 1); ls -= 2) {
    const float astep = -1.5707963267948966f / (float)(1 << ls);
    __syncthreads();
#pragma unroll
    for (int i = 0; i < NB / NTH; ++i) dif4<INV>(A, tid + NTH * i, ls, astep);
  }
  if (LM & 1) {
    __syncthreads();
#pragma unroll
    for (int i = 0; i < (M / 2) / NTH; ++i) r2pair(A, tid + NTH * i);
  }
  __syncthreads();
}

// Block-wide in-place DIT (forward): P-order -> natural.
template <int M>
__device__ __forceinline__ void dit_blk(float2* A) {
  constexpr int LM = LMof<M>::v;
  constexpr int NB = M / 4;
  const int tid = (int)threadIdx.x;
  if (LM & 1) {
    __syncthreads();
#pragma unroll
    for (int i = 0; i < (M / 2) / NTH; ++i) r2pair(A, tid + NTH * i);
  }
#pragma unroll
  for (int ls = (LM & 1); ls <= LM - 2; ls += 2) {
    const float astep = -1.5707963267948966f / (float)(1 << ls);
    __syncthreads();
#pragma unroll
    for (int i = 0; i < NB / NTH; ++i) dit4(A, tid + NTH * i, ls, astep);
  }
  __syncthreads();
}

// Lane-group FFTs, barrier-free (group-private slice, in-order LDS pipe).
// Requires LANES <= M/4.
template <int M, bool INV, int LANES>
__device__ __forceinline__ void dif_w(float2* Aw, int l) {
  constexpr int LM = LMof<M>::v;
  constexpr int NB = M / 4;
#pragma unroll
  for (int ls = LM - 2; ls >= (LM & 1); ls -= 2) {
    const float astep = -1.5707963267948966f / (float)(1 << ls);
#pragma unroll
    for (int i = 0; i < NB / LANES; ++i) dif4<INV>(Aw, l + LANES * i, ls, astep);
  }
  if (LM & 1) {
#pragma unroll
    for (int i = 0; i < (M / 2) / LANES; ++i) r2pair(Aw, l + LANES * i);
  }
}

template <int M, int LANES>
__device__ __forceinline__ void dit_w(float2* Aw, int l) {
  constexpr int LM = LMof<M>::v;
  constexpr int NB = M / 4;
  if (LM & 1) {
#pragma unroll
    for (int i = 0; i < (M / 2) / LANES; ++i) r2pair(Aw, l + LANES * i);
  }
#pragma unroll
  for (int ls = (LM & 1); ls <= LM - 2; ls += 2) {
    const float astep = -1.5707963267948966f / (float)(1 << ls);
#pragma unroll
    for (int i = 0; i < NB / LANES; ++i) dit4(Aw, l + LANES * i, ls, astep);
  }
}

// ---------------- Stage A: 2048-pt FFT per (b,c) signal ----------------
__global__ __launch_bounds__(NTH) void kA(const float* __restrict__ x,
                                          float2* __restrict__ xh) {
  __shared__ float2 A[2048];
  const int n = blockIdx.x, b = n / 6, c = n % 6;
  const float* xp = x + (size_t)b * (2048 * 6) + c;
#pragma unroll
  for (int i = 0; i < 8; ++i) {
    const int t = (int)threadIdx.x + NTH * i;
    A[swz(t)] = make_float2(xp[t * 6], 0.0f);
  }
  dif_blk<2048, false>(A);
#pragma unroll
  for (int i = 0; i < 8; ++i) {
    const int t = (int)threadIdx.x + NTH * i;
    xh[(size_t)n * 2048 + prevM<2048>(t)] = A[swz(t)];
  }
}

// ================= Fused B+C: parent first-order path, V kept in LDS =======

// Parent, block-wide, M1=1024 (j1 0..7). Leaves V (natural order, swizzled
// storage) intact in A. scr = separate small LDS scratch.
__device__ __forceinline__ void parent_blk1024(float2* A, float* scr,
                                               const float2* __restrict__ src,
                                               float* __restrict__ out,
                                               int b, int c, int j1) {
  constexpr int M1 = 1024;
  constexpr int NR = 4;
  const int tid = (int)threadIdx.x;
  const float xi = 0.4f * exp2f(-0.125f * (float)j1);
  const float sig = 0.1f * xi;
  const float i2s = 1.0f / (2.0f * sig * sig);
#pragma unroll
  for (int i = 0; i < NR; ++i) {
    const int m = tid + NTH * i;
    float2 acc = make_float2(0.0f, 0.0f);
#pragma unroll
    for (int q = 0; q < 2; ++q) {
      const int f = m + q * M1;
      const float fr = (float)(f < 1024 ? f : f - 2048) * (1.0f / 2048.0f);
      const float d = fr - xi;
      const float dd = d * d * i2s;
      if (dd < GCUT) {
        const float g = __expf(-dd);
        const float2 v = src[f];
        acc.x += v.x * g; acc.y += v.y * g;
      }
    }
    A[swz(m)] = acc;
  }
  dif_blk<M1, true>(A);
#pragma unroll
  for (int i = 0; i < NR; ++i) {
    const int m = tid + NTH * i;
    const float2 zv = A[swz(m)];
    A[swz(m)] = make_float2(sqrtf(zv.x * zv.x + zv.y * zv.y) * (1.0f / 2048.0f), 0.0f);
  }
  dit_blk<M1>(A);  // V natural (digit reversal cancels); KEEP in LDS.
  const float invM = 1.0f / (float)M1;
  const float c0 = A[0].x * invM;  // swz identity for idx<16
  const float2 U1 = A[1], U2 = A[2];
  const float k1 = PHI1 * 2.0f * invM, k2 = PHI2 * 2.0f * invM;
  float part = 0.0f;
#pragma unroll
  for (int i = 0; i < NR; ++i) {
    const int t = tid + NTH * i;
    float sv, cv;
    __sincosf((6.283185307179586f / (float)M1) * (float)t, &sv, &cv);
    float acc = c0 + k1 * (U1.x * cv - U1.y * sv);
    const float c2 = cv * cv - sv * sv, s2 = 2.0f * sv * cv;
    acc += k2 * (U2.x * c2 - U2.y * s2);
    part += __logf(acc + 1e-6f);
  }
  part = wsum<64>(part);
  const int lane = tid & 63, wid = tid >> 6;
  if (lane == 0) scr[wid] = part;
  __syncthreads();
  if (tid == 0)
    out[((size_t)b * 440 + j1) * 6 + c] = (scr[0] + scr[1] + scr[2] + scr[3]) * invM;
}

// Parent, per-wave (64 lanes), M1 in {512, 256}. V stays in Aw.
template <int M1>
__device__ __forceinline__ void parent_wav(float2* Aw, const float2* __restrict__ src,
                                           float* __restrict__ out,
                                           int b, int c, int j1, int l) {
  constexpr int NRW = M1 / 64;
  constexpr int F = 2048 / M1;
  const float xi = 0.4f * exp2f(-0.125f * (float)j1);
  const float sig = 0.1f * xi;
  const float i2s = 1.0f / (2.0f * sig * sig);
#pragma unroll
  for (int i = 0; i < NRW; ++i) {
    const int m = l + 64 * i;
    float2 acc = make_float2(0.0f, 0.0f);
#pragma unroll
    for (int q = 0; q < F; ++q) {
      const int f = m + q * M1;
      const float fr = (float)(f < 1024 ? f : f - 2048) * (1.0f / 2048.0f);
      const float d = fr - xi;
      const float dd = d * d * i2s;
      if (dd < GCUT) {
        const float g = __expf(-dd);
        const float2 v = src[f];
        acc.x += v.x * g; acc.y += v.y * g;
      }
    }
    Aw[swz(m)] = acc;
  }
  dif_w<M1, true, 64>(Aw, l);
#pragma unroll
  for (int i = 0; i < NRW; ++i) {
    const int m = l + 64 * i;
    const float2 zv = Aw[swz(m)];
    Aw[swz(m)] = make_float2(sqrtf(zv.x * zv.x + zv.y * zv.y) * (1.0f / 2048.0f), 0.0f);
  }
  dit_w<M1, 64>(Aw, l);  // V natural; KEEP.
  const float invM = 1.0f / (float)M1;
  const float c0 = Aw[0].x * invM;
  const float2 U1 = Aw[1], U2 = Aw[2];
  const float k1 = PHI1 * 2.0f * invM, k2 = PHI2 * 2.0f * invM;
  float part = 0.0f;
#pragma unroll
  for (int i = 0; i < NRW; ++i) {
    const int t = l + 64 * i;
    float sv, cv;
    __sincosf((6.283185307179586f / (float)M1) * (float)t, &sv, &cv);
    float acc = c0 + k1 * (U1.x * cv - U1.y * sv);
    const float c2 = cv * cv - sv * sv, s2 = 2.0f * sv * cv;
    acc += k2 * (U2.x * c2 - U2.y * s2);
    part += __logf(acc + 1e-6f);
  }
  part = wsum<64>(part);
  if (l == 0) out[((size_t)b * 440 + j1) * 6 + c] = part * invM;
}

// Parent, per-half-wave (32 lanes), M1=128. V stays in Ah.
__device__ __forceinline__ void parent_dual(float2* Ah, const float2* __restrict__ src,
                                            float* __restrict__ out,
                                            int b, int c, int j1, int ll) {
  const float xi = 0.4f * exp2f(-0.125f * (float)j1);
  const float sig = 0.1f * xi;
  const float i2s = 1.0f / (2.0f * sig * sig);
#pragma unroll
  for (int i = 0; i < 4; ++i) {
    const int m = ll + 32 * i;
    float2 acc = make_float2(0.0f, 0.0f);
#pragma unroll
    for (int q = 0; q < 16; ++q) {
      const int f = m + q * 128;
      const float fr = (float)(f < 1024 ? f : f - 2048) * (1.0f / 2048.0f);
      const float d = fr - xi;
      const float dd = d * d * i2s;
      if (dd < GCUT) {
        const float g = __expf(-dd);
        const float2 v = src[f];
        acc.x += v.x * g; acc.y += v.y * g;
      }
    }
    Ah[swz(m)] = acc;
  }
  dif_w<128, true, 32>(Ah, ll);
#pragma unroll
  for (int i = 0; i < 4; ++i) {
    const int m = ll + 32 * i;
    const float2 zv = Ah[swz(m)];
    Ah[swz(m)] = make_float2(sqrtf(zv.x * zv.x + zv.y * zv.y) * (1.0f / 2048.0f), 0.0f);
  }
  dit_w<128, 32>(Ah, ll);  // V natural; KEEP.
  const float invM = 1.0f / 128.0f;
  const float c0 = Ah[0].x * invM;
  const float2 U1 = Ah[1], U2 = Ah[2];
  const float k1 = PHI1 * 2.0f * invM, k2 = PHI2 * 2.0f * invM;
  float part = 0.0f;
#pragma unroll
  for (int i = 0; i < 4; ++i) {
    const int t = ll + 32 * i;
    float sv, cv;
    __sincosf((6.283185307179586f / 128.0f) * (float)t, &sv, &cv);
    float acc = c0 + k1 * (U1.x * cv - U1.y * sv);
    const float c2 = cv * cv - sv * sv, s2 = 2.0f * sv * cv;
    acc += k2 * (U2.x * c2 - U2.y * s2);
    part += __logf(acc + 1e-6f);
  }
  part = wsum<32>(part);
  if (ll == 0) out[((size_t)b * 440 + j1) * 6 + c] = part * invM;
}

// Descendant, per-wave (64 lanes). Used only in the o=0 class.
// No cvs/svs caching: caching spilled to scratch at the 64-VGPR tier (r1).
template <int M2>
__device__ __forceinline__ void desc_wav(float2* Aw, const float2* __restrict__ Vl,
                                         float* __restrict__ outp, int M1, int F,
                                         float xi, int l) {
  constexpr int NR2 = M2 / 64;
  const float sg = 0.8f * xi;
  const float i2s = 1.0f / (2.0f * sg * sg);
#pragma unroll
  for (int ii = 0; ii < NR2; ++ii) {
    const int m = l + 64 * ii;
    float2 acc = make_float2(0.0f, 0.0f);
    for (int q = 0; q < F; ++q) {
      const int f = m + q * M2;
      const float fr = (float)(f < (M1 >> 1) ? f : f - M1) * (1.0f / 2048.0f);
      const float d = fr - xi;
      const float dd = d * d * i2s;
      if (dd < GCUT) {
        const float g = __expf(-dd);
        const float2 vv = Vl[swz(f)];
        acc.x += vv.x * g; acc.y += vv.y * g;
      }
    }
    Aw[swz(m)] = acc;
  }
  dif_w<M2, true, 64>(Aw, l);
  const float invM1f = 1.0f / (float)M1;
  float b0 = 0, b1r = 0, b1i = 0, b2r = 0, b2i = 0;
#pragma unroll
  for (int ii = 0; ii < NR2; ++ii) {
    const int idx = l + 64 * ii;
    const float2 zv = Aw[swz(idx)];
    const float u = sqrtf(zv.x * zv.x + zv.y * zv.y) * invM1f;
    const int t = prevM<M2>(idx);
    float sv, cv;
    __sincosf((6.283185307179586f / (float)M2) * (float)t, &sv, &cv);
    b0 += u;
    b1r += u * cv; b1i -= u * sv;
    const float c2 = cv * cv - sv * sv, s2 = 2.0f * sv * cv;
    b2r += u * c2; b2i -= u * s2;
  }
  b0 = wsum<64>(b0);
  b1r = wsum<64>(b1r); b1i = wsum<64>(b1i);
  b2r = wsum<64>(b2r); b2i = wsum<64>(b2i);
  const float k1 = 2.0f * PHI1, k2 = 2.0f * PHI2;
  const float invM2 = 1.0f / (float)M2;
  float part = 0.0f;
#pragma unroll
  for (int ii = 0; ii < NR2; ++ii) {
    const int idx = l + 64 * ii;
    const int t = prevM<M2>(idx);
    float sv, cv;
    __sincosf((6.283185307179586f / (float)M2) * (float)t, &sv, &cv);
    float acc = b0 + k1 * (b1r * cv - b1i * sv);
    const float c2 = cv * cv - sv * sv, s2 = 2.0f * sv * cv;
    acc += k2 * (b2r * c2 - b2i * s2);
    part += __logf(acc * invM2 + 1e-6f);
  }
  part = wsum<64>(part);
  if (l == 0) *outp = part * invM2;
}

// Descendant, per-half-wave (32 lanes), M2 in {512, 256, 128}.
template <int M2>
__device__ __forceinline__ void desc_half(float2* Ah, const float2* __restrict__ Vl,
                                          float* __restrict__ outp, int M1, int F,
                                          float xi, int ll) {
  constexpr int NR2 = M2 / 32;
  const float sg = 0.8f * xi;
  const float i2s = 1.0f / (2.0f * sg * sg);
#pragma unroll
  for (int ii = 0; ii < NR2; ++ii) {
    const int m = ll + 32 * ii;
    float2 acc = make_float2(0.0f, 0.0f);
    for (int q = 0; q < F; ++q) {
      const int f = m + q * M2;
      const float fr = (float)(f < (M1 >> 1) ? f : f - M1) * (1.0f / 2048.0f);
      const float d = fr - xi;
      const float dd = d * d * i2s;
      if (dd < GCUT) {
        const float g = __expf(-dd);
        const float2 vv = Vl[swz(f)];
        acc.x += vv.x * g; acc.y += vv.y * g;
      }
    }
    Ah[swz(m)] = acc;
  }
  dif_w<M2, true, 32>(Ah, ll);
  const float invM1f = 1.0f / (float)M1;
  float b0 = 0, b1r = 0, b1i = 0, b2r = 0, b2i = 0;
#pragma unroll
  for (int ii = 0; ii < NR2; ++ii) {
    const int idx = ll + 32 * ii;
    const float2 zv = Ah[swz(idx)];
    const float u = sqrtf(zv.x * zv.x + zv.y * zv.y) * invM1f;
    const int t = prevM<M2>(idx);
    float sv, cv;
    __sincosf((6.283185307179586f / (float)M2) * (float)t, &sv, &cv);
    b0 += u;
    b1r += u * cv; b1i -= u * sv;
    const float c2 = cv * cv - sv * sv, s2 = 2.0f * sv * cv;
    b2r += u * c2; b2i -= u * s2;
  }
  b0 = wsum<32>(b0);
  b1r = wsum<32>(b1r); b1i = wsum<32>(b1i);
  b2r = wsum<32>(b2r); b2i = wsum<32>(b2i);
  const float k1 = 2.0f * PHI1, k2 = 2.0f * PHI2;
  const float invM2 = 1.0f / (float)M2;
  float part = 0.0f;
#pragma unroll
  for (int ii = 0; ii < NR2; ++ii) {
    const int idx = ll + 32 * ii;
    const int t = prevM<M2>(idx);
    float sv, cv;
    __sincosf((6.283185307179586f / (float)M2) * (float)t, &sv, &cv);
    float acc = b0 + k1 * (b1r * cv - b1i * sv);
    const float c2 = cv * cv - sv * sv, s2 = 2.0f * sv * cv;
    acc += k2 * (b2r * c2 - b2i * s2);
    part += __logf(acc * invM2 + 1e-6f);
  }
  part = wsum<32>(part);
  if (ll == 0) *outp = part * invM2;
}

// S2 output pointer for pair (j1, k): p = 4k(k-1)+j1.
__device__ __forceinline__ float* o2p(float* out, int b, int c, int j1, int k) {
  return out + ((size_t)b * 440 + 80 + 4 * k * (k - 1) + j1) * 6 + c;
}
__device__ __forceinline__ float xi2f(int k) { return 0.4f * exp2f(-(float)k); }

// kBC: 26 classes/signal (grid 1248 <= 1280 residency at 32KB LDS).
// Schedule rebalanced to minimize the max serial chain (r2: 60 -> ~36 rounds):
//  ci 0..7   o=0 (M1=1024): block parent; desc w0:k1 w1:k2+{k5,k6}
//            w2:k3+{k7,k8} w3:k4+{k9 h0}. chain ~31.
//  ci 8..11  o=1 (M1=512): 2 paths (A=8+2g on w0, B=9+2g on w1); desc as
//            HALF-wave units paired same-shape across halves (h0=A, h1=B):
//            w0: k2(512)+k9, w1: k3(256)+k8, w2: k4,k5, w3: k6,k7. chain ~33.
//  ci 12..15 o=2 (M1=256): same 2-path layout: w0: k3(256)+k9,
//            w1: k4,k5, w2: k6,k7, w3: k8. chain ~30.
//  ci 16..21 o=3,4,5 (M1=128): 4 paths/block, parents on halves of w0/w1;
//            desc round-robined over all 8 half-slots. chain <=36.
//  ci 22..25 o=6..9 (M1=128): 8 paths/block on halves; desc over 8 slots.
__global__ __launch_bounds__(NTH, 4) void kBC(const float2* __restrict__ xh,
                                              float* __restrict__ out) {
  __shared__ float2 L[4096];  // 32768 B
  const int ci = (int)blockIdx.x / 48;
  const int n  = (int)blockIdx.x % 48;
  const int b = n / 6, c = n % 6;
  const float2* src = xh + (size_t)n * 2048;
  const int tid = (int)threadIdx.x;
  const int wid = tid >> 6, l = tid & 63;
  const int h = l >> 5, ll = l & 31;
  const int slot = 2 * wid + h;

  if (ci < 8) {  // ---- o=0, M1=1024, block-wide parent ----
    const int j1 = ci;
    float* scr = (float*)(L + 3968);
    parent_blk1024(L, scr, src, out, b, c, j1);
    if (wid == 0) {
      desc_wav<1024>(L + 1024, L, o2p(out, b, c, j1, 1), 1024, 1, xi2f(1), l);
    } else if (wid == 1) {
      desc_wav<512>(L + 2048, L, o2p(out, b, c, j1, 2), 1024, 2, xi2f(2), l);
      const int k = 5 + h;
      desc_half<128>(L + 3328 + h * 128, L, o2p(out, b, c, j1, k), 1024, 8, xi2f(k), ll);
    } else if (wid == 2) {
      desc_wav<512>(L + 2560, L, o2p(out, b, c, j1, 3), 1024, 2, xi2f(3), l);
      const int k = 7 + h;
      desc_half<128>(L + 3584 + h * 128, L, o2p(out, b, c, j1, k), 1024, 8, xi2f(k), ll);
    } else {
      desc_wav<256>(L + 3072, L, o2p(out, b, c, j1, 4), 1024, 4, xi2f(4), l);
      if (h == 0)
        desc_half<128>(L + 3840, L, o2p(out, b, c, j1, 9), 1024, 8, xi2f(9), ll);
    }
  } else if (ci < 12) {  // ---- o=1, M1=512, 2 paths ----
    const int g = ci - 8;
    const int j1A = 8 + 2 * g, j1B = 9 + 2 * g;
    if (wid == 0)      parent_wav<512>(L,       src, out, b, c, j1A, l);
    else if (wid == 1) parent_wav<512>(L + 512, src, out, b, c, j1B, l);
    __syncthreads();
    const int j1 = h ? j1B : j1A;
    const float2* V = L + h * 512;
    if (wid == 0) {
      float2* W = L + 1024 + h * 512;
      desc_half<512>(W, V, o2p(out, b, c, j1, 2), 512, 1, xi2f(2), ll);
      desc_half<128>(W, V, o2p(out, b, c, j1, 9), 512, 4, xi2f(9), ll);
    } else if (wid == 1) {
      float2* W = L + 2048 + h * 256;
      desc_half<256>(W, V, o2p(out, b, c, j1, 3), 512, 2, xi2f(3), ll);
      desc_half<128>(W, V, o2p(out, b, c, j1, 8), 512, 4, xi2f(8), ll);
    } else if (wid == 2) {
      float2* W = L + 2560 + h * 128;
      desc_half<128>(W, V, o2p(out, b, c, j1, 4), 512, 4, xi2f(4), ll);
      desc_half<128>(W, V, o2p(out, b, c, j1, 5), 512, 4, xi2f(5), ll);
    } else {
      float2* W = L + 2816 + h * 128;
      desc_half<128>(W, V, o2p(out, b, c, j1, 6), 512, 4, xi2f(6), ll);
      desc_half<128>(W, V, o2p(out, b, c, j1, 7), 512, 4, xi2f(7), ll);
    }
  } else if (ci < 16) {  // ---- o=2, M1=256, 2 paths ----
    const int g = ci - 12;
    const int j1A = 16 + 2 * g, j1B = 17 + 2 * g;
    if (wid == 0)      parent_wav<256>(L,       src, out, b, c, j1A, l);
    else if (wid == 1) parent_wav<256>(L + 256, src, out, b, c, j1B, l);
    __syncthreads();
    const int j1 = h ? j1B : j1A;
    const float2* V = L + h * 256;
    if (wid == 0) {
      float2* W = L + 512 + h * 256;
      desc_half<256>(W, V, o2p(out, b, c, j1, 3), 256, 1, xi2f(3), ll);
      desc_half<128>(W, V, o2p(out, b, c, j1, 9), 256, 2, xi2f(9), ll);
    } else if (wid == 1) {
      float2* W = L + 1024 + h * 128;
      desc_half<128>(W, V, o2p(out, b, c, j1, 4), 256, 2, xi2f(4), ll);
      desc_half<128>(W, V, o2p(out, b, c, j1, 5), 256, 2, xi2f(5), ll);
    } else if (wid == 2) {
      float2* W = L + 1280 + h * 128;
      desc_half<128>(W, V, o2p(out, b, c, j1, 6), 256, 2, xi2f(6), ll);
      desc_half<128>(W, V, o2p(out, b, c, j1, 7), 256, 2, xi2f(7), ll);
    } else {
      float2* W = L + 1536 + h * 128;
      desc_half<128>(W, V, o2p(out, b, c, j1, 8), 256, 2, xi2f(8), ll);
    }
  } else if (ci < 22) {  // ---- o=3,4,5: 4 paths/block ----
    const int oo = 3 + ((ci - 16) >> 1);
    const int g = (ci - 16) & 1;
    const int j1base = 8 * oo + 4 * g;
    if (wid < 2)
      parent_dual(L + slot * 128, src, out, b, c, j1base + slot, ll);
    __syncthreads();
    float2* W = L + 1024 + slot * 128;
    if (oo == 3) {        // D=6, k=4..9; 24 descs, 3 per slot
#pragma unroll
      for (int i = 0; i < 3; ++i) {
        const int t = 3 * slot + i;
        const int p = t / 6, k = 4 + t % 6;
        desc_half<128>(W, L + p * 128, o2p(out, b, c, j1base + p, k), 128, 1, xi2f(k), ll);
      }
    } else if (oo == 4) {  // D=5, k=5..9; 20 descs: 2/slot + 1 extra on slots 0-3
#pragma unroll
      for (int i = 0; i < 2; ++i) {
        const int t = 2 * slot + i;
        const int p = t / 5, k = 5 + t % 5;
        desc_half<128>(W, L + p * 128, o2p(out, b, c, j1base + p, k), 128, 1, xi2f(k), ll);
      }
      if (slot < 4) {  // uniform per wave: w0/w1 slots all <4, w2/w3 all >=4
        const int t = 16 + slot;
        const int p = t / 5, k = 5 + t % 5;
        desc_half<128>(W, L + p * 128, o2p(out, b, c, j1base + p, k), 128, 1, xi2f(k), ll);
      }
    } else {              // D=4, k=6..9; 16 descs, 2 per slot
#pragma unroll
      for (int i = 0; i < 2; ++i) {
        const int t = 2 * slot + i;
        const int p = t >> 2, k = 6 + (t & 3);
        desc_half<128>(W, L + p * 128, o2p(out, b, c, j1base + p, k), 128, 1, xi2f(k), ll);
      }
    }
  } else {  // ---- o=6..9: 8 paths/block on half-slots ----
    const int oo = ci - 16;  // 6..9
    const int j1base = 8 * oo;
    parent_dual(L + slot * 128, src, out, b, c, j1base + slot, ll);
    __syncthreads();
    float2* W = L + 1024 + slot * 128;
    if (oo == 6) {        // D=3, k=7..9; 24 descs, 3 per slot
#pragma unroll
      for (int i = 0; i < 3; ++i) {
        const int t = 3 * slot + i;
        const int p = t / 3, k = 7 + t % 3;
        desc_half<128>(W, L + p * 128, o2p(out, b, c, j1base + p, k), 128, 1, xi2f(k), ll);
      }
    } else if (oo == 7) {  // D=2: each slot serves its own path
#pragma unroll
      for (int i = 0; i < 2; ++i) {
        const int k = 8 + i;
        desc_half<128>(W, L + slot * 128, o2p(out, b, c, j1base + slot, k), 128, 1, xi2f(k), ll);
      }
    } else if (oo == 8) {  // D=1
      desc_half<128>(W, L + slot * 128, o2p(out, b, c, j1base + slot, 9), 128, 1, xi2f(9), ll);
    }
    // oo == 9: parents only.
  }
}

extern "C" void kernel_launch(void* const* d_in, const int* in_sizes, int n_in,
                              void* d_out, int out_size, void* d_ws, size_t ws_size,
                              hipStream_t stream) {
  (void)in_sizes; (void)n_in; (void)out_size; (void)ws_size;
  const float* x = (const float*)d_in[0];  // [8, 2048, 6] fp32
  float* out = (float*)d_out;              // [8, 440, 6] fp32
  float2* xh = (float2*)d_ws;              // 48 * 2048 * 8 B = 786 KB
  kA<<<dim3(48), dim3(NTH), 0, stream>>>(x, xh);
  kBC<<<dim3(26 * 48), dim3(NTH), 0, stream>>>(xh, out);
}

// Round 4
// 86.953 us; speedup vs baseline: 1.4813x; 1.4813x over previous
//
#include <hip/hip_runtime.h>

#define NTH 256

#define PHI1 0.29504296f    // e^{-1.220703125}
#define PHI2 0.0075683594f  // e^{-4.8828125}
#define GCUT 18.0f          // Gaussian support cutoff: e^-18 = 1.5e-8

// Bank swizzle — conflict-free for all in-place strides; swz(i+128)=swz(i)+128.
__device__ __forceinline__ int swz(int i) { return i ^ (((i >> 4) & 3) * 5); }

__device__ __forceinline__ float2 cmul(float2 a, float2 b) {
  return make_float2(a.x * b.x - a.y * b.y, a.x * b.y + a.y * b.x);
}

template <int W>
__device__ __forceinline__ float wsum(float v) {
#pragma unroll
  for (int off = 1; off < W; off <<= 1) v += __shfl_xor(v, off, 64);
  return v;
}

// P(idx): output frequency of storage slot idx after the DIF stage sequence.
template <int M>
__device__ __forceinline__ int prevM(int i) {
  if (M == 128)
    return ((i >> 5) & 3) | (((i >> 3) & 3) << 2) | (((i >> 1) & 3) << 4) | ((i & 1) << 6);
  else if (M == 256)
    return ((i & 3) << 6) | (((i >> 2) & 3) << 4) | (((i >> 4) & 3) << 2) | ((i >> 6) & 3);
  else if (M == 512)
    return ((i >> 7) & 3) | (((i >> 5) & 3) << 2) | (((i >> 3) & 3) << 4) |
           (((i >> 1) & 3) << 6) | ((i & 1) << 8);
  else if (M == 1024)
    return ((i >> 8) & 3) | (((i >> 6) & 3) << 2) | (((i >> 4) & 3) << 4) |
           (((i >> 2) & 3) << 6) | ((i & 3) << 8);
  else
    return ((i >> 9) & 3) | (((i >> 7) & 3) << 2) | (((i >> 5) & 3) << 4) |
           (((i >> 3) & 3) << 6) | (((i >> 1) & 3) << 8) | ((i & 1) << 10);
}

// In-place radix-4 DIF stage; twiddles in registers.
template <bool INV>
__device__ __forceinline__ void dif4(float2* A, int j, int ls, float astep) {
  const int s = 1 << ls;
  const int e = j & (s - 1);
  const int base = ((j >> ls) << (ls + 2)) | e;
  float2 w1;
  __sincosf(astep * (float)e, &w1.y, &w1.x);
  if (INV) w1.y = -w1.y;
  const float2 w2 = cmul(w1, w1);
  const float2 w3 = cmul(w2, w1);
  const float2 a0 = A[swz(base)];
  const float2 a1 = A[swz(base + s)];
  const float2 a2 = A[swz(base + 2 * s)];
  const float2 a3 = A[swz(base + 3 * s)];
  const float t0x = a0.x + a2.x, t0y = a0.y + a2.y;
  const float t1x = a0.x - a2.x, t1y = a0.y - a2.y;
  const float t2x = a1.x + a3.x, t2y = a1.y + a3.y;
  const float bdx = a1.x - a3.x, bdy = a1.y - a3.y;
  const float sgn = INV ? -1.0f : 1.0f;
  const float t3x = sgn * bdy, t3y = -sgn * bdx;
  A[swz(base)]         = make_float2(t0x + t2x, t0y + t2y);
  A[swz(base + s)]     = cmul(make_float2(t1x + t3x, t1y + t3y), w1);
  A[swz(base + 2 * s)] = cmul(make_float2(t0x - t2x, t0y - t2y), w2);
  A[swz(base + 3 * s)] = cmul(make_float2(t1x - t3x, t1y - t3y), w3);
}

// In-place radix-4 DIT stage (transpose network; forward only).
__device__ __forceinline__ void dit4(float2* A, int j, int ls, float astep) {
  const int s = 1 << ls;
  const int e = j & (s - 1);
  const int base = ((j >> ls) << (ls + 2)) | e;
  float2 w1;
  __sincosf(astep * (float)e, &w1.y, &w1.x);
  const float2 w2 = cmul(w1, w1);
  const float2 w3 = cmul(w2, w1);
  const float2 c0 = A[swz(base)];
  const float2 c1 = cmul(A[swz(base + s)], w1);
  const float2 c2 = cmul(A[swz(base + 2 * s)], w2);
  const float2 c3 = cmul(A[swz(base + 3 * s)], w3);
  const float t0x = c0.x + c2.x, t0y = c0.y + c2.y;
  const float t1x = c0.x - c2.x, t1y = c0.y - c2.y;
  const float t2x = c1.x + c3.x, t2y = c1.y + c3.y;
  const float bdx = c1.x - c3.x, bdy = c1.y - c3.y;
  const float t3x = bdy, t3y = -bdx;
  A[swz(base)]         = make_float2(t0x + t2x, t0y + t2y);
  A[swz(base + s)]     = make_float2(t1x + t3x, t1y + t3y);
  A[swz(base + 2 * s)] = make_float2(t0x - t2x, t0y - t2y);
  A[swz(base + 3 * s)] = make_float2(t1x - t3x, t1y - t3y);
}

__device__ __forceinline__ void r2pair(float2* A, int g) {
  const float2 a = A[swz(2 * g)];
  const float2 b = A[swz(2 * g + 1)];
  A[swz(2 * g)]     = make_float2(a.x + b.x, a.y + b.y);
  A[swz(2 * g + 1)] = make_float2(a.x - b.x, a.y - b.y);
}

template <int M> struct LMof { static constexpr int v =
  (M == 2048) ? 11 : (M == 1024) ? 10 : (M == 512) ? 9 : (M == 256) ? 8 : 7; };

// Block-wide in-place DIF: natural -> P-order.
template <int M, bool INV>
__device__ __forceinline__ void dif_blk(float2* A) {
  constexpr int LM = LMof<M>::v;
  constexpr int NB = M / 4;
  const int tid = (int)threadIdx.x;
#pragma unroll
  for (int ls = LM - 2; ls >= (LM & 1); ls -= 2) {
    const float astep = -1.5707963267948966f / (float)(1 << ls);
    __syncthreads();
#pragma unroll
    for (int i = 0; i < NB / NTH; ++i) dif4<INV>(A, tid + NTH * i, ls, astep);
  }
  if (LM & 1) {
    __syncthreads();
#pragma unroll
    for (int i = 0; i < (M / 2) / NTH; ++i) r2pair(A, tid + NTH * i);
  }
  __syncthreads();
}

// Block-wide in-place DIT (forward): P-order -> natural.
template <int M>
__device__ __forceinline__ void dit_blk(float2* A) {
  constexpr int LM = LMof<M>::v;
  constexpr int NB = M / 4;
  const int tid = (int)threadIdx.x;
  if (LM & 1) {
    __syncthreads();
#pragma unroll
    for (int i = 0; i < (M / 2) / NTH; ++i) r2pair(A, tid + NTH * i);
  }
#pragma unroll
  for (int ls = (LM & 1); ls <= LM - 2; ls += 2) {
    const float astep = -1.5707963267948966f / (float)(1 << ls);
    __syncthreads();
#pragma unroll
    for (int i = 0; i < NB / NTH; ++i) dit4(A, tid + NTH * i, ls, astep);
  }
  __syncthreads();
}

// Lane-group FFTs, barrier-free (group-private slice, in-order LDS pipe).
template <int M, bool INV, int LANES>
__device__ __forceinline__ void dif_w(float2* Aw, int l) {
  constexpr int LM = LMof<M>::v;
  constexpr int NB = M / 4;
#pragma unroll
  for (int ls = LM - 2; ls >= (LM & 1); ls -= 2) {
    const float astep = -1.5707963267948966f / (float)(1 << ls);
#pragma unroll
    for (int i = 0; i < NB / LANES; ++i) dif4<INV>(Aw, l + LANES * i, ls, astep);
  }
  if (LM & 1) {
#pragma unroll
    for (int i = 0; i < (M / 2) / LANES; ++i) r2pair(Aw, l + LANES * i);
  }
}

template <int M, int LANES>
__device__ __forceinline__ void dit_w(float2* Aw, int l) {
  constexpr int LM = LMof<M>::v;
  constexpr int NB = M / 4;
  if (LM & 1) {
#pragma unroll
    for (int i = 0; i < (M / 2) / LANES; ++i) r2pair(Aw, l + LANES * i);
  }
#pragma unroll
  for (int ls = (LM & 1); ls <= LM - 2; ls += 2) {
    const float astep = -1.5707963267948966f / (float)(1 << ls);
#pragma unroll
    for (int i = 0; i < NB / LANES; ++i) dit4(Aw, l + LANES * i, ls, astep);
  }
}

// ---------------- Stage A: 2048-pt FFT per (b,c) signal ----------------
__global__ __launch_bounds__(NTH) void kA(const float* __restrict__ x,
                                          float2* __restrict__ xh) {
  __shared__ float2 A[2048];
  const int n = blockIdx.x, b = n / 6, c = n % 6;
  const float* xp = x + (size_t)b * (2048 * 6) + c;
#pragma unroll
  for (int i = 0; i < 8; ++i) {
    const int t = (int)threadIdx.x + NTH * i;
    A[swz(t)] = make_float2(xp[t * 6], 0.0f);
  }
  dif_blk<2048, false>(A);
#pragma unroll
  for (int i = 0; i < 8; ++i) {
    const int t = (int)threadIdx.x + NTH * i;
    xh[(size_t)n * 2048 + prevM<2048>(t)] = A[swz(t)];
  }
}

// ========= Fused B+C workers: __noinline__, ONE code copy each (I$ fix) ====
// LDS is dynamic; workers take element offsets and re-derive the addrspace(3)
// base via extern __shared__ inside the callee so ds_* ops are preserved.

// Parent, block-wide, M1=1024 (j1 0..7). Leaves V natural (swizzled) in L[0,1024).
__device__ __noinline__ void parent_blk1024(const float2* __restrict__ src,
                                            float* __restrict__ outp, int j1) {
  extern __shared__ float2 L[];
  float2* A = L;
  float* scr = (float*)(L + 3968);
  constexpr int M1 = 1024;
  constexpr int NR = 4;
  const int tid = (int)threadIdx.x;
  const float xi = 0.4f * exp2f(-0.125f * (float)j1);
  const float sig = 0.1f * xi;
  const float i2s = 1.0f / (2.0f * sig * sig);
#pragma unroll
  for (int i = 0; i < NR; ++i) {
    const int m = tid + NTH * i;
    float2 acc = make_float2(0.0f, 0.0f);
#pragma unroll
    for (int q = 0; q < 2; ++q) {
      const int f = m + q * M1;
      const float fr = (float)(f < 1024 ? f : f - 2048) * (1.0f / 2048.0f);
      const float d = fr - xi;
      const float dd = d * d * i2s;
      if (dd < GCUT) {
        const float g = __expf(-dd);
        const float2 v = src[f];
        acc.x += v.x * g; acc.y += v.y * g;
      }
    }
    A[swz(m)] = acc;
  }
  dif_blk<M1, true>(A);
#pragma unroll
  for (int i = 0; i < NR; ++i) {
    const int m = tid + NTH * i;
    const float2 zv = A[swz(m)];
    A[swz(m)] = make_float2(sqrtf(zv.x * zv.x + zv.y * zv.y) * (1.0f / 2048.0f), 0.0f);
  }
  dit_blk<M1>(A);  // V natural (digit reversal cancels); KEEP in LDS.
  const float invM = 1.0f / (float)M1;
  const float c0 = A[0].x * invM;  // swz identity for idx<16
  const float2 U1 = A[1], U2 = A[2];
  const float k1 = PHI1 * 2.0f * invM, k2 = PHI2 * 2.0f * invM;
  float part = 0.0f;
#pragma unroll
  for (int i = 0; i < NR; ++i) {
    const int t = tid + NTH * i;
    float sv, cv;
    __sincosf((6.283185307179586f / (float)M1) * (float)t, &sv, &cv);
    float acc = c0 + k1 * (U1.x * cv - U1.y * sv);
    const float c2 = cv * cv - sv * sv, s2 = 2.0f * sv * cv;
    acc += k2 * (U2.x * c2 - U2.y * s2);
    part += __logf(acc + 1e-6f);
  }
  part = wsum<64>(part);
  const int lane = tid & 63, wid = tid >> 6;
  if (lane == 0) scr[wid] = part;
  __syncthreads();
  if (tid == 0) *outp = (scr[0] + scr[1] + scr[2] + scr[3]) * invM;
}

// Parent, per-wave (64 lanes), M1 in {512, 256}. V stays at L[aoff, aoff+M1).
template <int M1>
__device__ __noinline__ void parent_wav(int aoff, const float2* __restrict__ src,
                                        float* __restrict__ outp, int j1, int l) {
  extern __shared__ float2 L[];
  float2* Aw = L + aoff;
  constexpr int NRW = M1 / 64;
  constexpr int F = 2048 / M1;
  const float xi = 0.4f * exp2f(-0.125f * (float)j1);
  const float sig = 0.1f * xi;
  const float i2s = 1.0f / (2.0f * sig * sig);
#pragma unroll
  for (int i = 0; i < NRW; ++i) {
    const int m = l + 64 * i;
    float2 acc = make_float2(0.0f, 0.0f);
#pragma unroll
    for (int q = 0; q < F; ++q) {
      const int f = m + q * M1;
      const float fr = (float)(f < 1024 ? f : f - 2048) * (1.0f / 2048.0f);
      const float d = fr - xi;
      const float dd = d * d * i2s;
      if (dd < GCUT) {
        const float g = __expf(-dd);
        const float2 v = src[f];
        acc.x += v.x * g; acc.y += v.y * g;
      }
    }
    Aw[swz(m)] = acc;
  }
  dif_w<M1, true, 64>(Aw, l);
#pragma unroll
  for (int i = 0; i < NRW; ++i) {
    const int m = l + 64 * i;
    const float2 zv = Aw[swz(m)];
    Aw[swz(m)] = make_float2(sqrtf(zv.x * zv.x + zv.y * zv.y) * (1.0f / 2048.0f), 0.0f);
  }
  dit_w<M1, 64>(Aw, l);  // V natural; KEEP.
  const float invM = 1.0f / (float)M1;
  const float c0 = Aw[0].x * invM;
  const float2 U1 = Aw[1], U2 = Aw[2];
  const float k1 = PHI1 * 2.0f * invM, k2 = PHI2 * 2.0f * invM;
  float part = 0.0f;
#pragma unroll
  for (int i = 0; i < NRW; ++i) {
    const int t = l + 64 * i;
    float sv, cv;
    __sincosf((6.283185307179586f / (float)M1) * (float)t, &sv, &cv);
    float acc = c0 + k1 * (U1.x * cv - U1.y * sv);
    const float c2 = cv * cv - sv * sv, s2 = 2.0f * sv * cv;
    acc += k2 * (U2.x * c2 - U2.y * s2);
    part += __logf(acc + 1e-6f);
  }
  part = wsum<64>(part);
  if (l == 0) *outp = part * invM;
}

// Parent, per-half-wave (32 lanes), M1=128. V stays at L[aoff, aoff+128).
__device__ __noinline__ void parent_dual(int aoff, const float2* __restrict__ src,
                                         float* __restrict__ outp, int j1, int ll) {
  extern __shared__ float2 L[];
  float2* Ah = L + aoff;
  const float xi = 0.4f * exp2f(-0.125f * (float)j1);
  const float sig = 0.1f * xi;
  const float i2s = 1.0f / (2.0f * sig * sig);
#pragma unroll
  for (int i = 0; i < 4; ++i) {
    const int m = ll + 32 * i;
    float2 acc = make_float2(0.0f, 0.0f);
#pragma unroll
    for (int q = 0; q < 16; ++q) {
      const int f = m + q * 128;
      const float fr = (float)(f < 1024 ? f : f - 2048) * (1.0f / 2048.0f);
      const float d = fr - xi;
      const float dd = d * d * i2s;
      if (dd < GCUT) {
        const float g = __expf(-dd);
        const float2 v = src[f];
        acc.x += v.x * g; acc.y += v.y * g;
      }
    }
    Ah[swz(m)] = acc;
  }
  dif_w<128, true, 32>(Ah, ll);
#pragma unroll
  for (int i = 0; i < 4; ++i) {
    const int m = ll + 32 * i;
    const float2 zv = Ah[swz(m)];
    Ah[swz(m)] = make_float2(sqrtf(zv.x * zv.x + zv.y * zv.y) * (1.0f / 2048.0f), 0.0f);
  }
  dit_w<128, 32>(Ah, ll);  // V natural; KEEP.
  const float invM = 1.0f / 128.0f;
  const float c0 = Ah[0].x * invM;
  const float2 U1 = Ah[1], U2 = Ah[2];
  const float k1 = PHI1 * 2.0f * invM, k2 = PHI2 * 2.0f * invM;
  float part = 0.0f;
#pragma unroll
  for (int i = 0; i < 4; ++i) {
    const int t = ll + 32 * i;
    float sv, cv;
    __sincosf((6.283185307179586f / 128.0f) * (float)t, &sv, &cv);
    float acc = c0 + k1 * (U1.x * cv - U1.y * sv);
    const float c2 = cv * cv - sv * sv, s2 = 2.0f * sv * cv;
    acc += k2 * (U2.x * c2 - U2.y * s2);
    part += __logf(acc + 1e-6f);
  }
  part = wsum<32>(part);
  if (ll == 0) *outp = part * invM;
}

// Descendant, per-wave (64 lanes). V read from LDS at voff (swizzled).
// No cvs/svs caching (spilled at 64-VGPR tier, r1).
template <int M2>
__device__ __noinline__ void desc_wav(int aoff, int voff, float* __restrict__ outp,
                                      int M1, int F, float xi, int l) {
  extern __shared__ float2 L[];
  float2* Aw = L + aoff;
  const float2* Vl = L + voff;
  constexpr int NR2 = M2 / 64;
  const float sg = 0.8f * xi;
  const float i2s = 1.0f / (2.0f * sg * sg);
#pragma unroll
  for (int ii = 0; ii < NR2; ++ii) {
    const int m = l + 64 * ii;
    float2 acc = make_float2(0.0f, 0.0f);
    for (int q = 0; q < F; ++q) {
      const int f = m + q * M2;
      const float fr = (float)(f < (M1 >> 1) ? f : f - M1) * (1.0f / 2048.0f);
      const float d = fr - xi;
      const float dd = d * d * i2s;
      if (dd < GCUT) {
        const float g = __expf(-dd);
        const float2 vv = Vl[swz(f)];
        acc.x += vv.x * g; acc.y += vv.y * g;
      }
    }
    Aw[swz(m)] = acc;
  }
  dif_w<M2, true, 64>(Aw, l);
  const float invM1f = 1.0f / (float)M1;
  float b0 = 0, b1r = 0, b1i = 0, b2r = 0, b2i = 0;
#pragma unroll
  for (int ii = 0; ii < NR2; ++ii) {
    const int idx = l + 64 * ii;
    const float2 zv = Aw[swz(idx)];
    const float u = sqrtf(zv.x * zv.x + zv.y * zv.y) * invM1f;
    const int t = prevM<M2>(idx);
    float sv, cv;
    __sincosf((6.283185307179586f / (float)M2) * (float)t, &sv, &cv);
    b0 += u;
    b1r += u * cv; b1i -= u * sv;
    const float c2 = cv * cv - sv * sv, s2 = 2.0f * sv * cv;
    b2r += u * c2; b2i -= u * s2;
  }
  b0 = wsum<64>(b0);
  b1r = wsum<64>(b1r); b1i = wsum<64>(b1i);
  b2r = wsum<64>(b2r); b2i = wsum<64>(b2i);
  const float k1 = 2.0f * PHI1, k2 = 2.0f * PHI2;
  const float invM2 = 1.0f / (float)M2;
  float part = 0.0f;
#pragma unroll
  for (int ii = 0; ii < NR2; ++ii) {
    const int idx = l + 64 * ii;
    const int t = prevM<M2>(idx);
    float sv, cv;
    __sincosf((6.283185307179586f / (float)M2) * (float)t, &sv, &cv);
    float acc = b0 + k1 * (b1r * cv - b1i * sv);
    const float c2 = cv * cv - sv * sv, s2 = 2.0f * sv * cv;
    acc += k2 * (b2r * c2 - b2i * s2);
    part += __logf(acc * invM2 + 1e-6f);
  }
  part = wsum<64>(part);
  if (l == 0) *outp = part * invM2;
}

// Descendant, per-half-wave (32 lanes), M2=128. V from LDS at voff (swizzled).
__device__ __noinline__ void desc_dual(int aoff, int voff, float* __restrict__ outp,
                                       int M1, int F, float xi, int ll) {
  extern __shared__ float2 L[];
  float2* Ah = L + aoff;
  const float2* Vl = L + voff;
  const float sg = 0.8f * xi;
  const float i2s = 1.0f / (2.0f * sg * sg);
#pragma unroll
  for (int ii = 0; ii < 4; ++ii) {
    const int m = ll + 32 * ii;
    float2 acc = make_float2(0.0f, 0.0f);
    for (int q = 0; q < F; ++q) {
      const int f = m + q * 128;
      const float fr = (float)(f < (M1 >> 1) ? f : f - M1) * (1.0f / 2048.0f);
      const float d = fr - xi;
      const float dd = d * d * i2s;
      if (dd < GCUT) {
        const float g = __expf(-dd);
        const float2 vv = Vl[swz(f)];
        acc.x += vv.x * g; acc.y += vv.y * g;
      }
    }
    Ah[swz(m)] = acc;
  }
  dif_w<128, true, 32>(Ah, ll);
  const float invM1f = 1.0f / (float)M1;
  float b0 = 0, b1r = 0, b1i = 0, b2r = 0, b2i = 0;
#pragma unroll
  for (int ii = 0; ii < 4; ++ii) {
    const int idx = ll + 32 * ii;
    const float2 zv = Ah[swz(idx)];
    const float u = sqrtf(zv.x * zv.x + zv.y * zv.y) * invM1f;
    const int t = prevM<128>(idx);
    float sv, cv;
    __sincosf((6.283185307179586f / 128.0f) * (float)t, &sv, &cv);
    b0 += u;
    b1r += u * cv; b1i -= u * sv;
    const float c2 = cv * cv - sv * sv, s2 = 2.0f * sv * cv;
    b2r += u * c2; b2i -= u * s2;
  }
  b0 = wsum<32>(b0);
  b1r = wsum<32>(b1r); b1i = wsum<32>(b1i);
  b2r = wsum<32>(b2r); b2i = wsum<32>(b2i);
  const float k1 = 2.0f * PHI1, k2 = 2.0f * PHI2;
  const float invM2 = 1.0f / 128.0f;
  float part = 0.0f;
#pragma unroll
  for (int ii = 0; ii < 4; ++ii) {
    const int idx = ll + 32 * ii;
    const int t = prevM<128>(idx);
    float sv, cv;
    __sincosf((6.283185307179586f / 128.0f) * (float)t, &sv, &cv);
    float acc = b0 + k1 * (b1r * cv - b1i * sv);
    const float c2 = cv * cv - sv * sv, s2 = 2.0f * sv * cv;
    acc += k2 * (b2r * c2 - b2i * s2);
    part += __logf(acc * invM2 + 1e-6f);
  }
  part = wsum<32>(part);
  if (ll == 0) *outp = part * invM2;
}

// Output pointers. S1: j1. S2 pair (j1, k): p = 4k(k-1)+j1.
__device__ __forceinline__ float* o1p(float* out, int b, int c, int j1) {
  return out + ((size_t)b * 440 + j1) * 6 + c;
}
__device__ __forceinline__ float* o2p(float* out, int b, int c, int j1, int k) {
  return out + ((size_t)b * 440 + 80 + 4 * k * (k - 1) + j1) * 6 + c;
}
__device__ __forceinline__ float xi2f(int k) { return 0.4f * exp2f(-(float)k); }

// kBC: round-2 schedule (19 classes/signal, 912 blocks), workers noinline.
//  [0,2)  o=1 (M1=512):  4 j1/block (wave-private), j1 = 8+4*ci+wid.
//  [2,4)  o=2 (M1=256):  j1 = 16+4*(ci-2)+wid.
//  [4,12) o=0 (M1=1024): block-wide parent, j1 = ci-4.
//  [12,19) o=3..9 (M1=128): 8 paths/block on half-waves, j1 = 8o+slot.
// Dynamic LDS: 4096 float2 = 32 KB -> 5 blocks/CU; grid needs 3.6 blocks/CU.
__global__ __launch_bounds__(NTH, 4) void kBC(const float2* __restrict__ xh,
                                              float* __restrict__ out) {
  extern __shared__ float2 L[];
  const int ci = (int)blockIdx.x / 48;
  const int n  = (int)blockIdx.x % 48;
  const int b = n / 6, c = n % 6;
  const float2* src = xh + (size_t)n * 2048;
  const int tid = (int)threadIdx.x;
  const int wid = tid >> 6, l = tid & 63;
  const int h = l >> 5, ll = l & 31;

  if (ci < 2) {  // ---- o=1, M1=512, wave-private ----
    const int j1 = 8 + 4 * ci + wid;
    const int a0 = wid * 1024;  // parent V: [a0, a0+512); work: [a0+512, a0+1024)
    parent_wav<512>(a0, src, o1p(out, b, c, j1), j1, l);
    desc_wav<512>(a0 + 512, a0, o2p(out, b, c, j1, 2), 512, 1, xi2f(2), l);
    desc_wav<256>(a0 + 512, a0, o2p(out, b, c, j1, 3), 512, 2, xi2f(3), l);
    for (int i = 0; i < 3; ++i) {
      const int k = 4 + 2 * i + h;  // h0: k4,k6,k8  h1: k5,k7,k9
      desc_dual(a0 + 512 + h * 128, a0, o2p(out, b, c, j1, k), 512, 4, xi2f(k), ll);
    }
  } else if (ci < 4) {  // ---- o=2, M1=256, wave-private ----
    const int j1 = 16 + 4 * (ci - 2) + wid;
    const int a0 = wid * 512;
    parent_wav<256>(a0, src, o1p(out, b, c, j1), j1, l);
    desc_wav<256>(a0 + 256, a0, o2p(out, b, c, j1, 3), 256, 1, xi2f(3), l);
    for (int i = 0; i < 3; ++i) {
      const int k = 4 + 2 * i + h;
      desc_dual(a0 + 256 + h * 128, a0, o2p(out, b, c, j1, k), 256, 2, xi2f(k), ll);
    }
  } else if (ci < 12) {  // ---- o=0, M1=1024, block-wide parent ----
    const int j1 = ci - 4;
    parent_blk1024(src, o1p(out, b, c, j1), j1);  // V final in L[0,1024)
    if (wid == 0) {
      desc_wav<1024>(1024, 0, o2p(out, b, c, j1, 1), 1024, 1, xi2f(1), l);
    } else if (wid == 1) {
      desc_wav<512>(2048, 0, o2p(out, b, c, j1, 2), 1024, 2, xi2f(2), l);
      const int k = 5 + h;
      desc_dual(3328 + h * 128, 0, o2p(out, b, c, j1, k), 1024, 8, xi2f(k), ll);
    } else if (wid == 2) {
      desc_wav<512>(2560, 0, o2p(out, b, c, j1, 3), 1024, 2, xi2f(3), l);
      const int k = 7 + h;
      desc_dual(3584 + h * 128, 0, o2p(out, b, c, j1, k), 1024, 8, xi2f(k), ll);
    } else {
      desc_wav<256>(3072, 0, o2p(out, b, c, j1, 4), 1024, 4, xi2f(4), l);
      if (h == 0)
        desc_dual(3840, 0, o2p(out, b, c, j1, 9), 1024, 8, xi2f(9), ll);
    }
  } else {  // ---- o=3..9, M1=128, half-wave-private ----
    const int o = ci - 9;  // 3..9
    const int slot = 2 * wid + h;
    const int j1 = 8 * o + slot;
    const int a0 = slot * 256;  // parent [a0, a0+128), work [a0+128, a0+256)
    parent_dual(a0, src, o1p(out, b, c, j1), j1, ll);
    for (int k = o + 1; k <= 9; ++k)
      desc_dual(a0 + 128, a0, o2p(out, b, c, j1, k), 128, 1, xi2f(k), ll);
  }
}

extern "C" void kernel_launch(void* const* d_in, const int* in_sizes, int n_in,
                              void* d_out, int out_size, void* d_ws, size_t ws_size,
                              hipStream_t stream) {
  (void)in_sizes; (void)n_in; (void)out_size; (void)ws_size;
  const float* x = (const float*)d_in[0];  // [8, 2048, 6] fp32
  float* out = (float*)d_out;              // [8, 440, 6] fp32
  float2* xh = (float2*)d_ws;              // 48 * 2048 * 8 B = 786 KB
  kA<<<dim3(48), dim3(NTH), 0, stream>>>(x, xh);
  kBC<<<dim3(19 * 48), dim3(NTH), 32768, stream>>>(xh, out);
}

// Round 5
// 83.883 us; speedup vs baseline: 1.5355x; 1.0366x over previous
//
#include <hip/hip_runtime.h>

#define NTH 256
#define U1H_STRIDE 21504  // 8*1024 + 8*512 + 8*256 + 56*128

#define PHI1 0.29504296f    // e^{-1.220703125}
#define PHI2 0.0075683594f  // e^{-4.8828125}
#define GCUT 18.0f          // Gaussian support cutoff: e^-18 = 1.5e-8

// Bank swizzle — conflict-free for all in-place strides; swz(i+128)=swz(i)+128.
__device__ __forceinline__ int swz(int i) { return i ^ (((i >> 4) & 3) * 5); }

__device__ __forceinline__ float2 cmul(float2 a, float2 b) {
  return make_float2(a.x * b.x - a.y * b.y, a.x * b.y + a.y * b.x);
}

template <int W>
__device__ __forceinline__ float wsum(float v) {
#pragma unroll
  for (int off = 1; off < W; off <<= 1) v += __shfl_xor(v, off, 64);
  return v;
}

// P(idx): output frequency of storage slot idx after the DIF stage sequence.
template <int M>
__device__ __forceinline__ int prevM(int i) {
  if (M == 128)
    return ((i >> 5) & 3) | (((i >> 3) & 3) << 2) | (((i >> 1) & 3) << 4) | ((i & 1) << 6);
  else if (M == 256)
    return ((i & 3) << 6) | (((i >> 2) & 3) << 4) | (((i >> 4) & 3) << 2) | ((i >> 6) & 3);
  else if (M == 512)
    return ((i >> 7) & 3) | (((i >> 5) & 3) << 2) | (((i >> 3) & 3) << 4) |
           (((i >> 1) & 3) << 6) | ((i & 1) << 8);
  else if (M == 1024)
    return ((i >> 8) & 3) | (((i >> 6) & 3) << 2) | (((i >> 4) & 3) << 4) |
           (((i >> 2) & 3) << 6) | ((i & 3) << 8);
  else
    return ((i >> 9) & 3) | (((i >> 7) & 3) << 2) | (((i >> 5) & 3) << 4) |
           (((i >> 3) & 3) << 6) | (((i >> 1) & 3) << 8) | ((i & 1) << 10);
}

// In-place radix-4 DIF stage; twiddles in registers.
template <bool INV>
__device__ __forceinline__ void dif4(float2* A, int j, int ls, float astep) {
  const int s = 1 << ls;
  const int e = j & (s - 1);
  const int base = ((j >> ls) << (ls + 2)) | e;
  float2 w1;
  __sincosf(astep * (float)e, &w1.y, &w1.x);
  if (INV) w1.y = -w1.y;
  const float2 w2 = cmul(w1, w1);
  const float2 w3 = cmul(w2, w1);
  const float2 a0 = A[swz(base)];
  const float2 a1 = A[swz(base + s)];
  const float2 a2 = A[swz(base + 2 * s)];
  const float2 a3 = A[swz(base + 3 * s)];
  const float t0x = a0.x + a2.x, t0y = a0.y + a2.y;
  const float t1x = a0.x - a2.x, t1y = a0.y - a2.y;
  const float t2x = a1.x + a3.x, t2y = a1.y + a3.y;
  const float bdx = a1.x - a3.x, bdy = a1.y - a3.y;
  const float sgn = INV ? -1.0f : 1.0f;
  const float t3x = sgn * bdy, t3y = -sgn * bdx;
  A[swz(base)]         = make_float2(t0x + t2x, t0y + t2y);
  A[swz(base + s)]     = cmul(make_float2(t1x + t3x, t1y + t3y), w1);
  A[swz(base + 2 * s)] = cmul(make_float2(t0x - t2x, t0y - t2y), w2);
  A[swz(base + 3 * s)] = cmul(make_float2(t1x - t3x, t1y - t3y), w3);
}

// In-place radix-4 DIT stage (transpose network; forward only).
__device__ __forceinline__ void dit4(float2* A, int j, int ls, float astep) {
  const int s = 1 << ls;
  const int e = j & (s - 1);
  const int base = ((j >> ls) << (ls + 2)) | e;
  float2 w1;
  __sincosf(astep * (float)e, &w1.y, &w1.x);
  const float2 w2 = cmul(w1, w1);
  const float2 w3 = cmul(w2, w1);
  const float2 c0 = A[swz(base)];
  const float2 c1 = cmul(A[swz(base + s)], w1);
  const float2 c2 = cmul(A[swz(base + 2 * s)], w2);
  const float2 c3 = cmul(A[swz(base + 3 * s)], w3);
  const float t0x = c0.x + c2.x, t0y = c0.y + c2.y;
  const float t1x = c0.x - c2.x, t1y = c0.y - c2.y;
  const float t2x = c1.x + c3.x, t2y = c1.y + c3.y;
  const float bdx = c1.x - c3.x, bdy = c1.y - c3.y;
  const float t3x = bdy, t3y = -bdx;
  A[swz(base)]         = make_float2(t0x + t2x, t0y + t2y);
  A[swz(base + s)]     = make_float2(t1x + t3x, t1y + t3y);
  A[swz(base + 2 * s)] = make_float2(t0x - t2x, t0y - t2y);
  A[swz(base + 3 * s)] = make_float2(t1x - t3x, t1y - t3y);
}

__device__ __forceinline__ void r2pair(float2* A, int g) {
  const float2 a = A[swz(2 * g)];
  const float2 b = A[swz(2 * g + 1)];
  A[swz(2 * g)]     = make_float2(a.x + b.x, a.y + b.y);
  A[swz(2 * g + 1)] = make_float2(a.x - b.x, a.y - b.y);
}

template <int M> struct LMof { static constexpr int v =
  (M == 2048) ? 11 : (M == 1024) ? 10 : (M == 512) ? 9 : (M == 256) ? 8 : 7; };

// Block-wide in-place DIF: natural -> P-order.
template <int M, bool INV>
__device__ __forceinline__ void dif_blk(float2* A) {
  constexpr int LM = LMof<M>::v;
  constexpr int NB = M / 4;
  const int tid = (int)threadIdx.x;
#pragma unroll
  for (int ls = LM - 2; ls >= (LM & 1); ls -= 2) {
    const float astep = -1.5707963267948966f / (float)(1 << ls);
    __syncthreads();
#pragma unroll
    for (int i = 0; i < NB / NTH; ++i) dif4<INV>(A, tid + NTH * i, ls, astep);
  }
  if (LM & 1) {
    __syncthreads();
#pragma unroll
    for (int i = 0; i < (M / 2) / NTH; ++i) r2pair(A, tid + NTH * i);
  }
  __syncthreads();
}

// Block-wide in-place DIT (forward): P-order -> natural.
template <int M>
__device__ __forceinline__ void dit_blk(float2* A) {
  constexpr int LM = LMof<M>::v;
  constexpr int NB = M / 4;
  const int tid = (int)threadIdx.x;
  if (LM & 1) {
    __syncthreads();
#pragma unroll
    for (int i = 0; i < (M / 2) / NTH; ++i) r2pair(A, tid + NTH * i);
  }
#pragma unroll
  for (int ls = (LM & 1); ls <= LM - 2; ls += 2) {
    const float astep = -1.5707963267948966f / (float)(1 << ls);
    __syncthreads();
#pragma unroll
    for (int i = 0; i < NB / NTH; ++i) dit4(A, tid + NTH * i, ls, astep);
  }
  __syncthreads();
}

// Lane-group FFTs, barrier-free (group-private slice, in-order LDS pipe).
template <int M, bool INV, int LANES>
__device__ __forceinline__ void dif_w(float2* Aw, int l) {
  constexpr int LM = LMof<M>::v;
  constexpr int NB = M / 4;
#pragma unroll
  for (int ls = LM - 2; ls >= (LM & 1); ls -= 2) {
    const float astep = -1.5707963267948966f / (float)(1 << ls);
#pragma unroll
    for (int i = 0; i < NB / LANES; ++i) dif4<INV>(Aw, l + LANES * i, ls, astep);
  }
  if (LM & 1) {
#pragma unroll
    for (int i = 0; i < (M / 2) / LANES; ++i) r2pair(Aw, l + LANES * i);
  }
}

template <int M, int LANES>
__device__ __forceinline__ void dit_w(float2* Aw, int l) {
  constexpr int LM = LMof<M>::v;
  constexpr int NB = M / 4;
  if (LM & 1) {
#pragma unroll
    for (int i = 0; i < (M / 2) / LANES; ++i) r2pair(Aw, l + LANES * i);
  }
#pragma unroll
  for (int ls = (LM & 1); ls <= LM - 2; ls += 2) {
    const float astep = -1.5707963267948966f / (float)(1 << ls);
#pragma unroll
    for (int i = 0; i < NB / LANES; ++i) dit4(Aw, l + LANES * i, ls, astep);
  }
}

// U1h layout: o=0:1024/path; o=1:512; o=2:256; o>=3:128.
__device__ __forceinline__ int u1h_off(int j1) {
  const int o = j1 >> 3;
  if (o == 0) return j1 * 1024;
  if (o == 1) return 8192 + (j1 - 8) * 512;
  if (o == 2) return 12288 + (j1 - 16) * 256;
  return 14336 + (j1 - 24) * 128;
}

__device__ __forceinline__ float* o1p(float* out, int b, int c, int j1) {
  return out + ((size_t)b * 440 + j1) * 6 + c;
}
__device__ __forceinline__ float* o2p(float* out, int b, int c, int j1, int k) {
  return out + ((size_t)b * 440 + 80 + 4 * k * (k - 1) + j1) * 6 + c;
}
__device__ __forceinline__ float xi2f(int k) { return 0.4f * exp2f(-(float)k); }

// ---------------- Stage A: 2048-pt FFT per (b,c) signal ----------------
__global__ __launch_bounds__(NTH) void kA(const float* __restrict__ x,
                                          float2* __restrict__ xh) {
  __shared__ float2 A[2048];
  const int n = blockIdx.x, b = n / 6, c = n % 6;
  const float* xp = x + (size_t)b * (2048 * 6) + c;
#pragma unroll
  for (int i = 0; i < 8; ++i) {
    const int t = (int)threadIdx.x + NTH * i;
    A[swz(t)] = make_float2(xp[t * 6], 0.0f);
  }
  dif_blk<2048, false>(A);
#pragma unroll
  for (int i = 0; i < 8; ++i) {
    const int t = (int)threadIdx.x + NTH * i;
    xh[(size_t)n * 2048 + prevM<2048>(t)] = A[swz(t)];
  }
}

// ================= Stage B: parents; V=U1h -> global; S1 out ===============
// All bodies force-inlined, no cached sincos arrays (spill discipline, r2).

// Block-wide, M1=1024 (j1 0..7).
__device__ __forceinline__ void pblk1024(float2* A, float* scr,
                                         const float2* __restrict__ src,
                                         float2* __restrict__ Vg,
                                         float* __restrict__ outp, int j1) {
  constexpr int M1 = 1024;
  const int tid = (int)threadIdx.x;
  const float xi = 0.4f * exp2f(-0.125f * (float)j1);
  const float sig = 0.1f * xi;
  const float i2s = 1.0f / (2.0f * sig * sig);
#pragma unroll
  for (int i = 0; i < 4; ++i) {
    const int m = tid + NTH * i;
    float2 acc = make_float2(0.0f, 0.0f);
#pragma unroll
    for (int q = 0; q < 2; ++q) {
      const int f = m + q * M1;
      const float fr = (float)(f < 1024 ? f : f - 2048) * (1.0f / 2048.0f);
      const float d = fr - xi;
      const float dd = d * d * i2s;
      if (dd < GCUT) {
        const float g = __expf(-dd);
        const float2 v = src[f];
        acc.x += v.x * g; acc.y += v.y * g;
      }
    }
    A[swz(m)] = acc;
  }
  dif_blk<M1, true>(A);
#pragma unroll
  for (int i = 0; i < 4; ++i) {
    const int m = tid + NTH * i;
    const float2 zv = A[swz(m)];
    A[swz(m)] = make_float2(sqrtf(zv.x * zv.x + zv.y * zv.y) * (1.0f / 2048.0f), 0.0f);
  }
  dit_blk<M1>(A);  // V natural (digit reversal cancels).
#pragma unroll
  for (int i = 0; i < 4; ++i) {  // writeback V (coalesced, natural order)
    const int m = tid + NTH * i;
    Vg[m] = A[swz(m)];
  }
  const float invM = 1.0f / (float)M1;
  const float c0 = A[0].x * invM;  // swz identity for idx<16
  const float2 U1 = A[1], U2 = A[2];
  const float k1 = PHI1 * 2.0f * invM, k2 = PHI2 * 2.0f * invM;
  float part = 0.0f;
#pragma unroll
  for (int i = 0; i < 4; ++i) {
    const int t = tid + NTH * i;
    float sv, cv;
    __sincosf((6.283185307179586f / (float)M1) * (float)t, &sv, &cv);
    float acc = c0 + k1 * (U1.x * cv - U1.y * sv);
    const float c2 = cv * cv - sv * sv, s2 = 2.0f * sv * cv;
    acc += k2 * (U2.x * c2 - U2.y * s2);
    part += __logf(acc + 1e-6f);
  }
  part = wsum<64>(part);
  const int lane = tid & 63, wid = tid >> 6;
  if (lane == 0) scr[wid] = part;
  __syncthreads();
  if (tid == 0) *outp = (scr[0] + scr[1] + scr[2] + scr[3]) * invM;
}

// Per-wave (64 lanes), M1 in {512, 256}.
template <int M1>
__device__ __forceinline__ void pwav(float2* Aw, const float2* __restrict__ src,
                                     float2* __restrict__ Vg,
                                     float* __restrict__ outp, int j1, int l) {
  constexpr int NRW = M1 / 64;
  constexpr int F = 2048 / M1;
  const float xi = 0.4f * exp2f(-0.125f * (float)j1);
  const float sig = 0.1f * xi;
  const float i2s = 1.0f / (2.0f * sig * sig);
#pragma unroll
  for (int i = 0; i < NRW; ++i) {
    const int m = l + 64 * i;
    float2 acc = make_float2(0.0f, 0.0f);
#pragma unroll
    for (int q = 0; q < F; ++q) {
      const int f = m + q * M1;
      const float fr = (float)(f < 1024 ? f : f - 2048) * (1.0f / 2048.0f);
      const float d = fr - xi;
      const float dd = d * d * i2s;
      if (dd < GCUT) {
        const float g = __expf(-dd);
        const float2 v = src[f];
        acc.x += v.x * g; acc.y += v.y * g;
      }
    }
    Aw[swz(m)] = acc;
  }
  dif_w<M1, true, 64>(Aw, l);
#pragma unroll
  for (int i = 0; i < NRW; ++i) {
    const int m = l + 64 * i;
    const float2 zv = Aw[swz(m)];
    Aw[swz(m)] = make_float2(sqrtf(zv.x * zv.x + zv.y * zv.y) * (1.0f / 2048.0f), 0.0f);
  }
  dit_w<M1, 64>(Aw, l);  // V natural
#pragma unroll
  for (int i = 0; i < NRW; ++i) {
    const int m = l + 64 * i;
    Vg[m] = Aw[swz(m)];
  }
  const float invM = 1.0f / (float)M1;
  const float c0 = Aw[0].x * invM;
  const float2 U1 = Aw[1], U2 = Aw[2];
  const float k1 = PHI1 * 2.0f * invM, k2 = PHI2 * 2.0f * invM;
  float part = 0.0f;
#pragma unroll
  for (int i = 0; i < NRW; ++i) {
    const int t = l + 64 * i;
    float sv, cv;
    __sincosf((6.283185307179586f / (float)M1) * (float)t, &sv, &cv);
    float acc = c0 + k1 * (U1.x * cv - U1.y * sv);
    const float c2 = cv * cv - sv * sv, s2 = 2.0f * sv * cv;
    acc += k2 * (U2.x * c2 - U2.y * s2);
    part += __logf(acc + 1e-6f);
  }
  part = wsum<64>(part);
  if (l == 0) *outp = part * invM;
}

// Per-half-wave (32 lanes), M1=128.
__device__ __forceinline__ void pdual(float2* Ah, const float2* __restrict__ src,
                                      float2* __restrict__ Vg,
                                      float* __restrict__ outp, int j1, int ll) {
  const float xi = 0.4f * exp2f(-0.125f * (float)j1);
  const float sig = 0.1f * xi;
  const float i2s = 1.0f / (2.0f * sig * sig);
#pragma unroll
  for (int i = 0; i < 4; ++i) {
    const int m = ll + 32 * i;
    float2 acc = make_float2(0.0f, 0.0f);
#pragma unroll
    for (int q = 0; q < 16; ++q) {
      const int f = m + q * 128;
      const float fr = (float)(f < 1024 ? f : f - 2048) * (1.0f / 2048.0f);
      const float d = fr - xi;
      const float dd = d * d * i2s;
      if (dd < GCUT) {
        const float g = __expf(-dd);
        const float2 v = src[f];
        acc.x += v.x * g; acc.y += v.y * g;
      }
    }
    Ah[swz(m)] = acc;
  }
  dif_w<128, true, 32>(Ah, ll);
#pragma unroll
  for (int i = 0; i < 4; ++i) {
    const int m = ll + 32 * i;
    const float2 zv = Ah[swz(m)];
    Ah[swz(m)] = make_float2(sqrtf(zv.x * zv.x + zv.y * zv.y) * (1.0f / 2048.0f), 0.0f);
  }
  dit_w<128, 32>(Ah, ll);  // V natural
#pragma unroll
  for (int i = 0; i < 4; ++i) {
    const int m = ll + 32 * i;
    Vg[m] = Ah[swz(m)];
  }
  const float invM = 1.0f / 128.0f;
  const float c0 = Ah[0].x * invM;
  const float2 U1 = Ah[1], U2 = Ah[2];
  const float k1 = PHI1 * 2.0f * invM, k2 = PHI2 * 2.0f * invM;
  float part = 0.0f;
#pragma unroll
  for (int i = 0; i < 4; ++i) {
    const int t = ll + 32 * i;
    float sv, cv;
    __sincosf((6.283185307179586f / 128.0f) * (float)t, &sv, &cv);
    float acc = c0 + k1 * (U1.x * cv - U1.y * sv);
    const float c2 = cv * cv - sv * sv, s2 = 2.0f * sv * cv;
    acc += k2 * (U2.x * c2 - U2.y * s2);
    part += __logf(acc + 1e-6f);
  }
  part = wsum<32>(part);
  if (ll == 0) *outp = part * invM;
}

// kB: 19 classes/signal (912 blocks). LDS 2080 float2 = 16.6 KB -> 9 blk/CU.
// [0,8) o=0 blk1024; [8,10) o=1 512wav x4; [10,12) o=2 256wav x4;
// [12,19) o>=3 128dual x8.
__global__ __launch_bounds__(NTH, 4) void kB(const float2* __restrict__ xh,
                                             float2* __restrict__ U1h,
                                             float* __restrict__ out) {
  __shared__ float2 A[2080];  // [2048,2080) = scratch floats
  const int ci = (int)blockIdx.x / 48;
  const int n  = (int)blockIdx.x % 48;
  const int b = n / 6, c = n % 6;
  const float2* src = xh + (size_t)n * 2048;
  float2* Vbase = U1h + (size_t)n * U1H_STRIDE;
  const int tid = (int)threadIdx.x;
  const int wid = tid >> 6, l = tid & 63;
  const int h = l >> 5, ll = l & 31;
  const int slot = 2 * wid + h;

  if (ci < 8) {
    const int j1 = ci;
    pblk1024(A, (float*)(A + 2048), src, Vbase + u1h_off(j1), o1p(out, b, c, j1), j1);
  } else if (ci < 10) {
    const int j1 = 8 + 4 * (ci - 8) + wid;
    pwav<512>(A + wid * 512, src, Vbase + u1h_off(j1), o1p(out, b, c, j1), j1, l);
  } else if (ci < 12) {
    const int j1 = 16 + 4 * (ci - 10) + wid;
    pwav<256>(A + wid * 256, src, Vbase + u1h_off(j1), o1p(out, b, c, j1), j1, l);
  } else {
    const int j1 = 24 + 8 * (ci - 12) + slot;
    pdual(A + slot * 128, src, Vbase + u1h_off(j1), o1p(out, b, c, j1), j1, ll);
  }
}

// ================= Stage C: descendants; V from global ====================

// Block-wide 3-bin DFT, M2=1024 (k=1 only; M1=1024, F=1).
__device__ __forceinline__ void dblk1024(float2* A, float* scr,
                                         const float2* __restrict__ Vg,
                                         float* __restrict__ outp, float xi) {
  constexpr int M2 = 1024;
  const int tid = (int)threadIdx.x;
  const float sg = 0.8f * xi;
  const float i2s = 1.0f / (2.0f * sg * sg);
#pragma unroll
  for (int ii = 0; ii < 4; ++ii) {
    const int m = tid + NTH * ii;
    float2 acc = make_float2(0.0f, 0.0f);
    const float fr = (float)(m < 512 ? m : m - 1024) * (1.0f / 2048.0f);
    const float d = fr - xi;
    const float dd = d * d * i2s;
    if (dd < GCUT) {
      const float g = __expf(-dd);
      const float2 vv = Vg[m];
      acc.x = vv.x * g; acc.y = vv.y * g;
    }
    A[swz(m)] = acc;
  }
  dif_blk<M2, true>(A);  // z2 in P-order
  const float invM1f = 1.0f / 1024.0f;
  float b0 = 0, b1r = 0, b1i = 0, b2r = 0, b2i = 0;
#pragma unroll
  for (int ii = 0; ii < 4; ++ii) {
    const int idx = tid + NTH * ii;
    const float2 zv = A[swz(idx)];
    const float u = sqrtf(zv.x * zv.x + zv.y * zv.y) * invM1f;
    const int t = prevM<M2>(idx);
    float sv, cv;
    __sincosf((6.283185307179586f / (float)M2) * (float)t, &sv, &cv);
    b0 += u;
    b1r += u * cv; b1i -= u * sv;
    const float c2 = cv * cv - sv * sv, s2 = 2.0f * sv * cv;
    b2r += u * c2; b2i -= u * s2;
  }
  b0 = wsum<64>(b0);
  b1r = wsum<64>(b1r); b1i = wsum<64>(b1i);
  b2r = wsum<64>(b2r); b2i = wsum<64>(b2i);
  const int lane = tid & 63, wid = tid >> 6;
  if (lane == 0) {
    scr[wid * 5 + 0] = b0;
    scr[wid * 5 + 1] = b1r; scr[wid * 5 + 2] = b1i;
    scr[wid * 5 + 3] = b2r; scr[wid * 5 + 4] = b2i;
  }
  __syncthreads();
  float Bv[5];
#pragma unroll
  for (int bi = 0; bi < 5; ++bi)
    Bv[bi] = scr[bi] + scr[5 + bi] + scr[10 + bi] + scr[15 + bi];
  const float k1 = 2.0f * PHI1, k2 = 2.0f * PHI2;
  const float invM2 = 1.0f / (float)M2;
  float part = 0.0f;
#pragma unroll
  for (int ii = 0; ii < 4; ++ii) {
    const int idx = tid + NTH * ii;
    const int t = prevM<M2>(idx);
    float sv, cv;
    __sincosf((6.283185307179586f / (float)M2) * (float)t, &sv, &cv);
    float acc = Bv[0] + k1 * (Bv[1] * cv - Bv[2] * sv);
    const float c2 = cv * cv - sv * sv, s2 = 2.0f * sv * cv;
    acc += k2 * (Bv[3] * c2 - Bv[4] * s2);
    part += __logf(acc * invM2 + 1e-6f);
  }
  part = wsum<64>(part);
  if (lane == 0) scr[20 + wid] = part;
  __syncthreads();
  if (tid == 0) *outp = (scr[20] + scr[21] + scr[22] + scr[23]) * invM2;
}

// Per-wave descendant, M2 in {512, 256}. No cached sincos arrays.
template <int M2>
__device__ __forceinline__ void dwav(float2* Aw, const float2* __restrict__ Vg,
                                     float* __restrict__ outp, int M1, int F,
                                     float xi, int l) {
  constexpr int NR2 = M2 / 64;
  const float sg = 0.8f * xi;
  const float i2s = 1.0f / (2.0f * sg * sg);
#pragma unroll
  for (int ii = 0; ii < NR2; ++ii) {
    const int m = l + 64 * ii;
    float2 acc = make_float2(0.0f, 0.0f);
    for (int q = 0; q < F; ++q) {
      const int f = m + q * M2;
      const float fr = (float)(f < (M1 >> 1) ? f : f - M1) * (1.0f / 2048.0f);
      const float d = fr - xi;
      const float dd = d * d * i2s;
      if (dd < GCUT) {
        const float g = __expf(-dd);
        const float2 vv = Vg[f];
        acc.x += vv.x * g; acc.y += vv.y * g;
      }
    }
    Aw[swz(m)] = acc;
  }
  dif_w<M2, true, 64>(Aw, l);
  const float invM1f = 1.0f / (float)M1;
  float b0 = 0, b1r = 0, b1i = 0, b2r = 0, b2i = 0;
#pragma unroll
  for (int ii = 0; ii < NR2; ++ii) {
    const int idx = l + 64 * ii;
    const float2 zv = Aw[swz(idx)];
    const float u = sqrtf(zv.x * zv.x + zv.y * zv.y) * invM1f;
    const int t = prevM<M2>(idx);
    float sv, cv;
    __sincosf((6.283185307179586f / (float)M2) * (float)t, &sv, &cv);
    b0 += u;
    b1r += u * cv; b1i -= u * sv;
    const float c2 = cv * cv - sv * sv, s2 = 2.0f * sv * cv;
    b2r += u * c2; b2i -= u * s2;
  }
  b0 = wsum<64>(b0);
  b1r = wsum<64>(b1r); b1i = wsum<64>(b1i);
  b2r = wsum<64>(b2r); b2i = wsum<64>(b2i);
  const float k1 = 2.0f * PHI1, k2 = 2.0f * PHI2;
  const float invM2 = 1.0f / (float)M2;
  float part = 0.0f;
#pragma unroll
  for (int ii = 0; ii < NR2; ++ii) {
    const int idx = l + 64 * ii;
    const int t = prevM<M2>(idx);
    float sv, cv;
    __sincosf((6.283185307179586f / (float)M2) * (float)t, &sv, &cv);
    float acc = b0 + k1 * (b1r * cv - b1i * sv);
    const float c2 = cv * cv - sv * sv, s2 = 2.0f * sv * cv;
    acc += k2 * (b2r * c2 - b2i * s2);
    part += __logf(acc * invM2 + 1e-6f);
  }
  part = wsum<64>(part);
  if (l == 0) *outp = part * invM2;
}

// Per-half-wave descendant, M2=128.
__device__ __forceinline__ void ddual(float2* Ah, const float2* __restrict__ Vg,
                                      float* __restrict__ outp, int M1, int F,
                                      float xi, int ll) {
  const float sg = 0.8f * xi;
  const float i2s = 1.0f / (2.0f * sg * sg);
#pragma unroll
  for (int ii = 0; ii < 4; ++ii) {
    const int m = ll + 32 * ii;
    float2 acc = make_float2(0.0f, 0.0f);
    for (int q = 0; q < F; ++q) {
      const int f = m + q * 128;
      const float fr = (float)(f < (M1 >> 1) ? f : f - M1) * (1.0f / 2048.0f);
      const float d = fr - xi;
      const float dd = d * d * i2s;
      if (dd < GCUT) {
        const float g = __expf(-dd);
        const float2 vv = Vg[f];
        acc.x += vv.x * g; acc.y += vv.y * g;
      }
    }
    Ah[swz(m)] = acc;
  }
  dif_w<128, true, 32>(Ah, ll);
  const float invM1f = 1.0f / (float)M1;
  float b0 = 0, b1r = 0, b1i = 0, b2r = 0, b2i = 0;
#pragma unroll
  for (int ii = 0; ii < 4; ++ii) {
    const int idx = ll + 32 * ii;
    const float2 zv = Ah[swz(idx)];
    const float u = sqrtf(zv.x * zv.x + zv.y * zv.y) * invM1f;
    const int t = prevM<128>(idx);
    float sv, cv;
    __sincosf((6.283185307179586f / 128.0f) * (float)t, &sv, &cv);
    b0 += u;
    b1r += u * cv; b1i -= u * sv;
    const float c2 = cv * cv - sv * sv, s2 = 2.0f * sv * cv;
    b2r += u * c2; b2i -= u * s2;
  }
  b0 = wsum<32>(b0);
  b1r = wsum<32>(b1r); b1i = wsum<32>(b1i);
  b2r = wsum<32>(b2r); b2i = wsum<32>(b2i);
  const float k1 = 2.0f * PHI1, k2 = 2.0f * PHI2;
  const float invM2 = 1.0f / 128.0f;
  float part = 0.0f;
#pragma unroll
  for (int ii = 0; ii < 4; ++ii) {
    const int idx = ll + 32 * ii;
    const int t = prevM<128>(idx);
    float sv, cv;
    __sincosf((6.283185307179586f / 128.0f) * (float)t, &sv, &cv);
    float acc = b0 + k1 * (b1r * cv - b1i * sv);
    const float c2 = cv * cv - sv * sv, s2 = 2.0f * sv * cv;
    acc += k2 * (b2r * c2 - b2i * s2);
    part += __logf(acc * invM2 + 1e-6f);
  }
  part = wsum<32>(part);
  if (ll == 0) *outp = part * invM2;
}

// kC: 58 classes/signal (2784 blocks), one descendant per slot, no chaining.
// [0,8)   k=1: dblk1024, j1=ci.
// [8,12)  k=2: dwav<512> x4, p=4(ci-8)+wid, j1=p; M1 = p<8?1024:512.
// [12,14) k=3 j1 0-7: dwav<512> x4, M1=1024 F=2.
// [14,18) k=3 j1 8-23: dwav<256> x4; M1 = j1<16?512:256.
// [18,20) k=4 j1 0-7: dwav<256> x4, M1=1024 F=4.
// [20,23) k=4 j1 8-31: ddual x8; M1 by octave.
// [23,58) k=5..9: ddual x8; k blocks per k.
__global__ __launch_bounds__(NTH, 4) void kC(const float2* __restrict__ U1h,
                                             float* __restrict__ out) {
  __shared__ float2 W[2048];
  __shared__ float scr[24];
  const int ci = (int)blockIdx.x / 48;
  const int n  = (int)blockIdx.x % 48;
  const int b = n / 6, c = n % 6;
  const float2* Vbase = U1h + (size_t)n * U1H_STRIDE;
  const int tid = (int)threadIdx.x;
  const int wid = tid >> 6, l = tid & 63;
  const int h = l >> 5, ll = l & 31;
  const int slot = 2 * wid + h;

  if (ci < 8) {
    const int j1 = ci;
    dblk1024(W, scr, Vbase + u1h_off(j1), o2p(out, b, c, j1, 1), xi2f(1));
  } else if (ci < 12) {
    const int j1 = 4 * (ci - 8) + wid;  // 0..15
    const int M1 = (j1 < 8) ? 1024 : 512;
    dwav<512>(W + wid * 512, Vbase + u1h_off(j1), o2p(out, b, c, j1, 2),
              M1, M1 / 512, xi2f(2), l);
  } else if (ci < 14) {
    const int j1 = 4 * (ci - 12) + wid;  // 0..7
    dwav<512>(W + wid * 512, Vbase + u1h_off(j1), o2p(out, b, c, j1, 3),
              1024, 2, xi2f(3), l);
  } else if (ci < 18) {
    const int j1 = 8 + 4 * (ci - 14) + wid;  // 8..23
    const int M1 = (j1 < 16) ? 512 : 256;
    dwav<256>(W + wid * 256, Vbase + u1h_off(j1), o2p(out, b, c, j1, 3),
              M1, M1 / 256, xi2f(3), l);
  } else if (ci < 20) {
    const int j1 = 4 * (ci - 18) + wid;  // 0..7
    dwav<256>(W + wid * 256, Vbase + u1h_off(j1), o2p(out, b, c, j1, 4),
              1024, 4, xi2f(4), l);
  } else if (ci < 23) {
    const int j1 = 8 + 8 * (ci - 20) + slot;  // 8..31
    const int o = j1 >> 3;                    // 1..3
    const int M1 = (o < 3) ? (1024 >> o) : 128;
    ddual(W + slot * 128, Vbase + u1h_off(j1), o2p(out, b, c, j1, 4),
          M1, M1 / 128, xi2f(4), ll);
  } else {
    int g = ci - 23;  // k blocks per k, k=5..9
    int k = 5;
    while (g >= k) { g -= k; ++k; }
    const int j1 = 8 * g + slot;  // octave o = g
    const int M1 = (g < 3) ? (1024 >> g) : 128;
    ddual(W + slot * 128, Vbase + u1h_off(j1), o2p(out, b, c, j1, k),
          M1, M1 / 128, xi2f(k), ll);
  }
}

extern "C" void kernel_launch(void* const* d_in, const int* in_sizes, int n_in,
                              void* d_out, int out_size, void* d_ws, size_t ws_size,
                              hipStream_t stream) {
  (void)in_sizes; (void)n_in; (void)out_size; (void)ws_size;
  const float* x = (const float*)d_in[0];  // [8, 2048, 6] fp32
  float* out = (float*)d_out;              // [8, 440, 6] fp32
  float2* U1h = (float2*)d_ws;                                       // 8.26 MB
  float2* xh = (float2*)((char*)d_ws + (size_t)48 * U1H_STRIDE * sizeof(float2));
  kA<<<dim3(48), dim3(NTH), 0, stream>>>(x, xh);
  kB<<<dim3(19 * 48), dim3(NTH), 0, stream>>>(xh, U1h, out);
  kC<<<dim3(58 * 48), dim3(NTH), 0, stream>>>(U1h, out);
}